// Round 1
// baseline (623.486 us; speedup 1.0000x reference)
//
#include <hip/hip_runtime.h>
#include <hip/hip_bf16.h>
#include <math.h>

// ---------------------------------------------------------------------------
// CRGainHopLayerAnnealed: n=8192, in_dim=256, out_dim=128, d_sub=64, K1=3
// Pipeline:
//   Z_k = hop_k @ W_k^T                  [3,8192,64]   (fp32 tiled GEMM)
//   Hp  = H @ W_out^T                    [8192,128]
//   G_k = Z_k^T Z_k                      [3,64,64]     (atomic partial sums)
//   M_k = I + c*G_k ; logdet via trace series; Minv via Newton-Schulz
//   w   = softmax(norm(delta_R)/tau) ; s_k = ETA*c*w_k
//   QT_k = s_k * W_out @ (Minv_k W_k)^T  [3,128,64] -> packed [128,192]
//   pre = Hp + Zcat @ QTcat^T            [8192,128]
//   pre += -ETA*LAMBDA * L @ Hp          (bf16 MFMA, split-K, atomics)
//   out = LN(softthresh(pre))            + tail: w, dR_norm, delta_R
// ---------------------------------------------------------------------------

#define COEFF 0.03125f        // d/(n*eps^2) = 64/(8192*0.25)
#define SCL_LAP (-0.15f)      // -ETA*LAMBDA_LAP

typedef __attribute__((ext_vector_type(8))) short short8;
typedef __attribute__((ext_vector_type(4))) float f32x4;

__device__ __forceinline__ unsigned short f2bf_bits(float f) {
  unsigned int u = __float_as_uint(f);
  unsigned int r = (u + 0x7fffu + ((u >> 16) & 1u)) >> 16;   // RNE
  return (unsigned short)r;
}

// ---------------- generic tiled GEMM: C = scale * A (*) B [+ addC] ---------
// BM=BN=64, BK=16, 256 threads, 4x4 micro-tile. transB=1: C=A*B^T ; 0: C=A*B
__global__ __launch_bounds__(256) void gemm_tile(
    const float* __restrict__ A, const float* __restrict__ B,
    float* __restrict__ C, const float* __restrict__ addC,
    const float* __restrict__ scale_ptr,
    int K, int lda, int ldb, int ldc, int ldadd,
    long sA, long sB, long sC, int transB) {
  __shared__ float As[64][17];
  __shared__ float Bs[64][17];
  const int tid = threadIdx.x;
  const int tx = tid & 15, ty = tid >> 4;
  const int m0 = blockIdx.y * 64, n0 = blockIdx.x * 64;
  const int b = blockIdx.z;
  A += (size_t)b * sA; B += (size_t)b * sB; C += (size_t)b * sC;
  float cc[4][4];
#pragma unroll
  for (int i = 0; i < 4; ++i)
#pragma unroll
    for (int j = 0; j < 4; ++j) cc[i][j] = 0.f;
  const int lr = tid >> 2, lc = (tid & 3) << 2;
  for (int k0 = 0; k0 < K; k0 += 16) {
    float4 av = *(const float4*)(A + (size_t)(m0 + lr) * lda + k0 + lc);
    As[lr][lc] = av.x; As[lr][lc + 1] = av.y; As[lr][lc + 2] = av.z; As[lr][lc + 3] = av.w;
    if (transB) {
      float4 bv = *(const float4*)(B + (size_t)(n0 + lr) * ldb + k0 + lc);
      Bs[lr][lc] = bv.x; Bs[lr][lc + 1] = bv.y; Bs[lr][lc + 2] = bv.z; Bs[lr][lc + 3] = bv.w;
    } else {
      int kk = tid & 15, n4 = (tid >> 4) << 2;
      float4 bv = *(const float4*)(B + (size_t)(k0 + kk) * ldb + n0 + n4);
      Bs[n4][kk] = bv.x; Bs[n4 + 1][kk] = bv.y; Bs[n4 + 2][kk] = bv.z; Bs[n4 + 3][kk] = bv.w;
    }
    __syncthreads();
#pragma unroll
    for (int kk = 0; kk < 16; ++kk) {
      float a[4], bb[4];
#pragma unroll
      for (int i = 0; i < 4; ++i) a[i] = As[ty * 4 + i][kk];
#pragma unroll
      for (int j = 0; j < 4; ++j) bb[j] = Bs[tx * 4 + j][kk];
#pragma unroll
      for (int i = 0; i < 4; ++i)
#pragma unroll
        for (int j = 0; j < 4; ++j) cc[i][j] = fmaf(a[i], bb[j], cc[i][j]);
    }
    __syncthreads();
  }
  float scale = scale_ptr ? scale_ptr[b] : 1.0f;
#pragma unroll
  for (int i = 0; i < 4; ++i)
#pragma unroll
    for (int j = 0; j < 4; ++j) {
      int m = m0 + ty * 4 + i, n = n0 + tx * 4 + j;
      float v = cc[i][j] * scale;
      if (addC) v += addC[(size_t)m * ldadd + n];
      C[(size_t)m * ldc + n] = v;
    }
}

// ---------------- Gram: G[k] += Z_k^T Z_k (Z packed [8192][192]) -----------
__global__ __launch_bounds__(256) void gram_kernel(const float* __restrict__ Z,
                                                   float* __restrict__ G) {
  __shared__ float Zs[64][65];
  const int k = blockIdx.y, tid = threadIdx.x;
  const int d0 = (tid & 15) * 4, e0 = (tid >> 4) * 4;
  float acc[4][4];
#pragma unroll
  for (int i = 0; i < 4; ++i)
#pragma unroll
    for (int j = 0; j < 4; ++j) acc[i][j] = 0.f;
  for (int c = 0; c < 4; ++c) {
    int nb = blockIdx.x * 256 + c * 64;
    for (int idx = tid; idx < 1024; idx += 256) {
      int rr = idx >> 4, c4 = (idx & 15) * 4;
      float4 v = *(const float4*)(Z + (size_t)(nb + rr) * 192 + k * 64 + c4);
      Zs[rr][c4] = v.x; Zs[rr][c4 + 1] = v.y; Zs[rr][c4 + 2] = v.z; Zs[rr][c4 + 3] = v.w;
    }
    __syncthreads();
    for (int rr = 0; rr < 64; ++rr) {
      float zd[4], ze[4];
#pragma unroll
      for (int i = 0; i < 4; ++i) { zd[i] = Zs[rr][d0 + i]; ze[i] = Zs[rr][e0 + i]; }
#pragma unroll
      for (int i = 0; i < 4; ++i)
#pragma unroll
        for (int j = 0; j < 4; ++j) acc[i][j] = fmaf(zd[i], ze[j], acc[i][j]);
    }
    __syncthreads();
  }
#pragma unroll
  for (int i = 0; i < 4; ++i)
#pragma unroll
    for (int j = 0; j < 4; ++j)
      atomicAdd(&G[k * 4096 + (d0 + i) * 64 + (e0 + j)], acc[i][j]);
}

// ---------------- per-hop 64x64 linear algebra -----------------------------
__device__ float blocksum(float v, float* scr) {
  int tid = threadIdx.x;
#pragma unroll
  for (int o = 32; o; o >>= 1) v += __shfl_xor(v, o);
  __syncthreads();
  if ((tid & 63) == 0) scr[tid >> 6] = v;
  __syncthreads();
  if (tid == 0) {
    float s = 0.f;
    for (int i = 0; i < 16; ++i) s += scr[i];
    scr[16] = s;
  }
  __syncthreads();
  return scr[16];
}

__device__ void gemm64(const float* X, const float* Y, float cc[2][2]) {
  int tx = threadIdx.x & 31, ty = threadIdx.x >> 5;
  cc[0][0] = cc[0][1] = cc[1][0] = cc[1][1] = 0.f;
  for (int kk = 0; kk < 64; ++kk) {
    float a0 = X[(ty * 2) * 64 + kk], a1 = X[(ty * 2 + 1) * 64 + kk];
    float b0 = Y[kk * 64 + tx * 2], b1 = Y[kk * 64 + tx * 2 + 1];
    cc[0][0] = fmaf(a0, b0, cc[0][0]); cc[0][1] = fmaf(a0, b1, cc[0][1]);
    cc[1][0] = fmaf(a1, b0, cc[1][0]); cc[1][1] = fmaf(a1, b1, cc[1][1]);
  }
}

__device__ void writeback64(float* D, const float cc[2][2]) {
  int tx = threadIdx.x & 31, ty = threadIdx.x >> 5;
  D[(ty * 2) * 64 + tx * 2] = cc[0][0];
  D[(ty * 2) * 64 + tx * 2 + 1] = cc[0][1];
  D[(ty * 2 + 1) * 64 + tx * 2] = cc[1][0];
  D[(ty * 2 + 1) * 64 + tx * 2 + 1] = cc[1][1];
}

__device__ float dotAB(const float* X, const float* Y, float* scr) {
  int tx = threadIdx.x & 31, ty = threadIdx.x >> 5;
  float v = 0.f;
#pragma unroll
  for (int i = 0; i < 2; ++i)
#pragma unroll
    for (int j = 0; j < 2; ++j) {
      int r = ty * 2 + i, c = tx * 2 + j;
      v += X[r * 64 + c] * Y[r * 64 + c];
    }
  return blocksum(v, scr);
}

// grid=3 blocks, 1024 thr. Computes R[k]=0.5*logdet(M_k) and Minv_k.
__global__ __launch_bounds__(1024) void smallk(const float* __restrict__ G,
                                               float* __restrict__ Minv,
                                               float* __restrict__ Rout) {
  __shared__ float B0[4096];  // E (persistent)
  __shared__ float B1[4096];  // E2 -> X
  __shared__ float B2[4096];  // E4 -> E6 -> E8 -> T
  __shared__ float scr[20];
  const int k = blockIdx.x, tid = threadIdx.x;
  const float* Gk = G + k * 4096;
  // M = I + coeff*G
  for (int i = tid; i < 4096; i += 1024) {
    int r = i >> 6, c = i & 63;
    B0[i] = COEFF * Gk[i] + (r == c ? 1.f : 0.f);
  }
  __syncthreads();
  // Gershgorin (wave 0; M symmetric so column sums = row sums, conflict-free)
  if (tid < 64) {
    float rs = 0.f, dg = B0[tid * 65];
    for (int j = 0; j < 64; ++j) rs += fabsf(B0[j * 64 + tid]);
    float lo = 2.f * dg - rs, hi = rs;
#pragma unroll
    for (int o = 32; o; o >>= 1) {
      lo = fminf(lo, __shfl_xor(lo, o));
      hi = fmaxf(hi, __shfl_xor(hi, o));
    }
    if (tid == 0) scr[17] = 0.5f * (fmaxf(lo, 1.f) + hi);
  }
  __syncthreads();
  const float alpha = scr[17], inva = 1.f / alpha;
  // E = M/alpha - I (in place)
  for (int i = tid; i < 4096; i += 1024) {
    int r = i >> 6, c = i & 63;
    B0[i] = B0[i] * inva - (r == c ? 1.f : 0.f);
  }
  __syncthreads();
  // trace series: logdet(I+E) = sum (-1)^{j+1} tr(E^j)/j, j=1..10
  int tx = tid & 31, ty = tid >> 5;
  float v1 = 0.f, v2 = 0.f;
#pragma unroll
  for (int i = 0; i < 2; ++i)
#pragma unroll
    for (int j = 0; j < 2; ++j) {
      int r = ty * 2 + i, c = tx * 2 + j;
      float e = B0[r * 64 + c];
      if (r == c) v1 += e;
      v2 += e * e;
    }
  float t1 = blocksum(v1, scr);
  float t2 = blocksum(v2, scr);
  float cc[2][2];
  gemm64(B0, B0, cc); writeback64(B1, cc); __syncthreads();        // E2
  float t3 = dotAB(B1, B0, scr);
  float t4 = dotAB(B1, B1, scr);
  gemm64(B1, B1, cc); writeback64(B2, cc); __syncthreads();        // E4
  float t5 = dotAB(B2, B0, scr);
  float t6 = dotAB(B2, B1, scr);
  gemm64(B2, B1, cc); __syncthreads(); writeback64(B2, cc); __syncthreads(); // E6
  float t7 = dotAB(B2, B0, scr);
  float t8 = dotAB(B2, B1, scr);
  gemm64(B2, B1, cc); __syncthreads(); writeback64(B2, cc); __syncthreads(); // E8
  float t9 = dotAB(B2, B0, scr);
  float t10 = dotAB(B2, B1, scr);
  if (tid == 0) {
    float ld = 64.f * logf(alpha) + t1 - t2 / 2.f + t3 / 3.f - t4 / 4.f + t5 / 5.f
               - t6 / 6.f + t7 / 7.f - t8 / 8.f + t9 / 9.f - t10 / 10.f;
    Rout[k] = 0.5f * ld;
  }
  // Newton-Schulz: X0 = I - E; X <- X(2I - (I+E)X), 3 iters
  for (int i = tid; i < 4096; i += 1024) {
    int r = i >> 6, c = i & 63;
    B1[i] = (r == c ? 1.f : 0.f) - B0[i];
  }
  __syncthreads();
  for (int it = 0; it < 3; ++it) {
    gemm64(B0, B1, cc);  // E*X
    {                    // T = E*X + X -> B2
      int px = threadIdx.x & 31, py = threadIdx.x >> 5;
      B2[(py * 2) * 64 + px * 2] = cc[0][0] + B1[(py * 2) * 64 + px * 2];
      B2[(py * 2) * 64 + px * 2 + 1] = cc[0][1] + B1[(py * 2) * 64 + px * 2 + 1];
      B2[(py * 2 + 1) * 64 + px * 2] = cc[1][0] + B1[(py * 2 + 1) * 64 + px * 2];
      B2[(py * 2 + 1) * 64 + px * 2 + 1] = cc[1][1] + B1[(py * 2 + 1) * 64 + px * 2 + 1];
    }
    __syncthreads();
    gemm64(B1, B2, cc);  // X*T
    __syncthreads();
    {                    // X = 2X - X*T (in place, own elements)
      int px = threadIdx.x & 31, py = threadIdx.x >> 5;
      B1[(py * 2) * 64 + px * 2] = 2.f * B1[(py * 2) * 64 + px * 2] - cc[0][0];
      B1[(py * 2) * 64 + px * 2 + 1] = 2.f * B1[(py * 2) * 64 + px * 2 + 1] - cc[0][1];
      B1[(py * 2 + 1) * 64 + px * 2] = 2.f * B1[(py * 2 + 1) * 64 + px * 2] - cc[1][0];
      B1[(py * 2 + 1) * 64 + px * 2 + 1] = 2.f * B1[(py * 2 + 1) * 64 + px * 2 + 1] - cc[1][1];
    }
    __syncthreads();
  }
  for (int i = tid; i < 4096; i += 1024) Minv[k * 4096 + i] = B1[i] * inva;
}

// ---------------- weights / tail outputs -----------------------------------
__global__ void small_w(const float* __restrict__ R, const float* __restrict__ tauP,
                        float* __restrict__ tail, float* __restrict__ sb) {
  if (threadIdx.x != 0) return;
  float R0 = R[0], R1 = R[1], R2 = R[2];
  float d0 = R0, d1 = R1 - R0, d2 = R2 - R1;
  float mean = (d0 + d1 + d2) * (1.f / 3.f);
  float e0 = d0 - mean, e1 = d1 - mean, e2 = d2 - mean;
  float sd = sqrtf((e0 * e0 + e1 * e1 + e2 * e2) * 0.5f) + 1e-6f;
  float n0 = e0 / sd, n1 = e1 / sd, n2 = e2 / sd;
  float tau = tauP[0];
  float x0 = n0 / tau, x1 = n1 / tau, x2 = n2 / tau;
  float mx = fmaxf(x0, fmaxf(x1, x2));
  float w0 = expf(x0 - mx), w1 = expf(x1 - mx), w2 = expf(x2 - mx);
  float s = w0 + w1 + w2;
  w0 /= s; w1 /= s; w2 /= s;
  tail[0] = w0; tail[1] = w1; tail[2] = w2;
  tail[3] = n0; tail[4] = n1; tail[5] = n2;
  tail[6] = d0; tail[7] = d1; tail[8] = d2;
  sb[0] = 0.015625f * w0; sb[1] = 0.015625f * w1; sb[2] = 0.015625f * w2;  // ETA*coeff*w
}

// ---------------- Hp -> HpT bf16 (transpose + convert) ---------------------
__global__ __launch_bounds__(256) void transpose_cvt(const float* __restrict__ Hp,
                                                     unsigned short* __restrict__ HpT) {
  __shared__ float T[32][33];
  const int cb = blockIdx.x, rb = blockIdx.y, tid = threadIdx.x;
  int r = tid >> 3, c4 = (tid & 7) * 4;
  float4 v = *(const float4*)(Hp + (size_t)(rb * 32 + r) * 128 + cb * 32 + c4);
  T[r][c4] = v.x; T[r][c4 + 1] = v.y; T[r][c4 + 2] = v.z; T[r][c4 + 3] = v.w;
  __syncthreads();
  int c = tid >> 3, r4 = (tid & 7) * 4;
  ushort4 u;
  u.x = f2bf_bits(T[r4][c]); u.y = f2bf_bits(T[r4 + 1][c]);
  u.z = f2bf_bits(T[r4 + 2][c]); u.w = f2bf_bits(T[r4 + 3][c]);
  *(ushort4*)(HpT + (size_t)(cb * 32 + c) * 8192 + rb * 32 + r4) = u;
}

// ---------------- big MFMA GEMM: pre += -0.15 * L @ Hp ---------------------
// grid (64 m-blocks, 8 k-splits), 256 thr. BM=128, BN=128, BK=32.
__global__ __launch_bounds__(256) void big_gemm(const float* __restrict__ Lp,
                                                const unsigned short* __restrict__ HpT,
                                                float* __restrict__ pre) {
  __shared__ __align__(16) unsigned short As[128][40];
  __shared__ __align__(16) unsigned short Bs[128][40];
  const int tid = threadIdx.x;
  const int wave = tid >> 6, lane = tid & 63;
  const int m0 = blockIdx.x * 128;
  const int kbase = blockIdx.y * 1024;
  const int ar = tid >> 1, ah = (tid & 1) * 16;
  const size_t lrow = (size_t)(m0 + ar) * 8192;
  const size_t brow = (size_t)ar * 8192;
  f32x4 acc[2][8];
#pragma unroll
  for (int i = 0; i < 2; ++i)
#pragma unroll
    for (int j = 0; j < 8; ++j) acc[i][j] = (f32x4){0.f, 0.f, 0.f, 0.f};
  float4 apf[4];
  uint4 bpf[2];
  {
    const float* ap = Lp + lrow + kbase + ah;
    apf[0] = *(const float4*)(ap); apf[1] = *(const float4*)(ap + 4);
    apf[2] = *(const float4*)(ap + 8); apf[3] = *(const float4*)(ap + 12);
    const unsigned short* bp = HpT + brow + kbase + ah;
    bpf[0] = *(const uint4*)(bp); bpf[1] = *(const uint4*)(bp + 8);
  }
  const int quad = lane >> 4, mcol = lane & 15;
  for (int step = 0; step < 32; ++step) {
    __syncthreads();
    {
      __attribute__((aligned(16))) unsigned short tmp[16];
      const float* f = (const float*)apf;
#pragma unroll
      for (int i = 0; i < 16; ++i) tmp[i] = f2bf_bits(f[i]);
      *(uint4*)&As[ar][ah] = *(const uint4*)&tmp[0];
      *(uint4*)&As[ar][ah + 8] = *(const uint4*)&tmp[8];
      *(uint4*)&Bs[ar][ah] = bpf[0];
      *(uint4*)&Bs[ar][ah + 8] = bpf[1];
    }
    __syncthreads();
    if (step < 31) {  // prefetch next tile (overlaps MFMA below)
      int kc = kbase + (step + 1) * 32;
      const float* ap = Lp + lrow + kc + ah;
      apf[0] = *(const float4*)(ap); apf[1] = *(const float4*)(ap + 4);
      apf[2] = *(const float4*)(ap + 8); apf[3] = *(const float4*)(ap + 12);
      const unsigned short* bp = HpT + brow + kc + ah;
      bpf[0] = *(const uint4*)(bp); bpf[1] = *(const uint4*)(bp + 8);
    }
    short8 af0 = *(const short8*)&As[wave * 32 + mcol][quad * 8];
    short8 af1 = *(const short8*)&As[wave * 32 + 16 + mcol][quad * 8];
#pragma unroll
    for (int nt = 0; nt < 8; ++nt) {
      short8 bf = *(const short8*)&Bs[nt * 16 + mcol][quad * 8];
      acc[0][nt] = __builtin_amdgcn_mfma_f32_16x16x32_bf16(af0, bf, acc[0][nt], 0, 0, 0);
      acc[1][nt] = __builtin_amdgcn_mfma_f32_16x16x32_bf16(af1, bf, acc[1][nt], 0, 0, 0);
    }
  }
#pragma unroll
  for (int mt = 0; mt < 2; ++mt)
#pragma unroll
    for (int nt = 0; nt < 8; ++nt)
#pragma unroll
      for (int r = 0; r < 4; ++r) {
        int grow = m0 + wave * 32 + mt * 16 + quad * 4 + r;
        int gcol = nt * 16 + mcol;
        atomicAdd(pre + (size_t)grow * 128 + gcol, SCL_LAP * acc[mt][nt][r]);
      }
}

// ---------------- soft-threshold + LayerNorm -------------------------------
__global__ __launch_bounds__(256) void finish_kernel(
    const float* __restrict__ pre, const float* __restrict__ thr,
    const float* __restrict__ gamma, const float* __restrict__ beta,
    float* __restrict__ out) {
  const int lane = threadIdx.x & 63;
  const int row = blockIdx.x * 4 + (threadIdx.x >> 6);
  const float* p = pre + (size_t)row * 128;
  float x0 = p[lane], x1 = p[lane + 64];
  float t0 = fabsf(thr[lane]), t1 = fabsf(thr[lane + 64]);
  float a0 = fmaxf(fabsf(x0) - t0, 0.f); float s0 = (x0 >= 0.f) ? a0 : -a0;
  float a1 = fmaxf(fabsf(x1) - t1, 0.f); float s1 = (x1 >= 0.f) ? a1 : -a1;
  float sum = s0 + s1;
#pragma unroll
  for (int o = 32; o; o >>= 1) sum += __shfl_xor(sum, o);
  float mean = sum * (1.f / 128.f);
  float d0 = s0 - mean, d1 = s1 - mean;
  float ss = d0 * d0 + d1 * d1;
#pragma unroll
  for (int o = 32; o; o >>= 1) ss += __shfl_xor(ss, o);
  float inv = rsqrtf(ss * (1.f / 128.f) + 1e-5f);
  out[(size_t)row * 128 + lane] = d0 * inv * gamma[lane] + beta[lane];
  out[(size_t)row * 128 + lane + 64] = d1 * inv * gamma[lane + 64] + beta[lane + 64];
}

// ---------------------------------------------------------------------------
extern "C" void kernel_launch(void* const* d_in, const int* in_sizes, int n_in,
                              void* d_out, int out_size, void* d_ws, size_t ws_size,
                              hipStream_t stream) {
  const float* H = (const float*)d_in[0];
  const float* hop = (const float*)d_in[1];
  const float* L = (const float*)d_in[2];
  const float* Wst = (const float*)d_in[3];
  const float* Wout = (const float*)d_in[4];
  const float* thr = (const float*)d_in[5];
  const float* gamma = (const float*)d_in[6];
  const float* beta = (const float*)d_in[7];
  const float* tau = (const float*)d_in[8];
  float* out = (float*)d_out;

  float* ws = (float*)d_ws;
  float* Zbuf = ws;                       // [8192][192] packed Z (k*64+d)
  float* Hp = Zbuf + 1572864;             // [8192][128]
  float* pre = Hp + 1048576;              // [8192][128]
  float* Gb = pre + 1048576;              // [3][64][64]
  float* Minv = Gb + 12288;               // [3][64][64]
  float* Rb = Minv + 12288;               // [3]
  float* sb = Rb + 16;                    // [3]
  float* C1 = sb + 16;                    // [3][64][256]
  float* QT = C1 + 49152;                 // [128][192] packed QT
  unsigned short* HpT = (unsigned short*)(QT + 24576);  // [128][8192] bf16

  hipMemsetAsync(Gb, 0, 12288 * sizeof(float), stream);

  // Z_k = hop_k @ W_k^T  -> Zbuf cols [k*64, k*64+64)
  gemm_tile<<<dim3(1, 128, 3), 256, 0, stream>>>(
      hop, Wst, Zbuf, nullptr, nullptr, 256, 256, 256, 192, 0,
      2097152L, 16384L, 64L, 1);
  // Hp = H @ W_out^T
  gemm_tile<<<dim3(2, 128, 1), 256, 0, stream>>>(
      H, Wout, Hp, nullptr, nullptr, 256, 256, 256, 128, 0, 0L, 0L, 0L, 1);
  // G_k
  gram_kernel<<<dim3(32, 3), 256, 0, stream>>>(Zbuf, Gb);
  // logdet + inverse
  smallk<<<dim3(3), 1024, 0, stream>>>(Gb, Minv, Rb);
  // weights + tail outputs
  small_w<<<dim3(1), 64, 0, stream>>>(Rb, tau, out + 1048576, sb);
  // C1_k = Minv_k @ W_k   (NN)
  gemm_tile<<<dim3(4, 1, 3), 256, 0, stream>>>(
      Minv, Wst, C1, nullptr, nullptr, 64, 64, 256, 256, 0,
      4096L, 16384L, 16384L, 0);
  // QT_k = s_k * W_out @ C1_k^T  -> QT cols [k*64, k*64+64)
  gemm_tile<<<dim3(1, 2, 3), 256, 0, stream>>>(
      Wout, C1, QT, nullptr, sb, 256, 256, 256, 192, 0,
      0L, 16384L, 64L, 1);
  // pre = Hp + Zbuf @ QT^T
  gemm_tile<<<dim3(2, 128, 1), 256, 0, stream>>>(
      Zbuf, QT, pre, Hp, nullptr, 192, 192, 192, 128, 128, 0L, 0L, 0L, 1);
  // HpT bf16
  transpose_cvt<<<dim3(4, 256), 256, 0, stream>>>(Hp, HpT);
  // pre += -0.15 * L @ Hp
  big_gemm<<<dim3(64, 8), 256, 0, stream>>>(L, HpT, pre);
  // out = LN(softthresh(pre))
  finish_kernel<<<dim3(2048), 256, 0, stream>>>(pre, thr, gamma, beta, out);

  (void)in_sizes; (void)n_in; (void)out_size; (void)ws_size;
}

// Round 2
// 559.801 us; speedup vs baseline: 1.1138x; 1.1138x over previous
//
#include <hip/hip_runtime.h>
#include <hip/hip_bf16.h>
#include <math.h>

// ---------------------------------------------------------------------------
// CRGainHopLayerAnnealed: n=8192, in_dim=256, out_dim=128, d_sub=64, K1=3
//   Hp  = H @ W_out^T ; HpT = bf16(Hp^T)
//   Z_k = hop_k @ W_k^T ; Gpart (per-block partial Grams, no atomics)
//   P_k = W_out @ W_k^T (independent, early)
//   fused dispatch: blocks 0-2  -> smallk (logdet series + Newton-Schulz inv)
//                   blocks 3-514-> split-K bf16 MFMA  Pbuf[s] = (L @ Hp)-partial
//   QT_k = s_k * P_k @ Minv_k  (Minv symmetric)
//   pre  = Hp + Zcat @ QTcat^T
//   out  = LN(softthresh(pre - 0.15 * sum_s Pbuf[s]))  + tail (w, dRn, dR)
// ---------------------------------------------------------------------------

#define COEFF 0.03125f        // d/(n*eps^2) = 64/(8192*0.25)
#define SCL_LAP (-0.15f)      // -ETA*LAMBDA_LAP

typedef __attribute__((ext_vector_type(8))) short short8;
typedef __attribute__((ext_vector_type(4))) float f32x4;

__device__ __forceinline__ unsigned short f2bf_bits(float f) {
  unsigned int u = __float_as_uint(f);
  unsigned int r = (u + 0x7fffu + ((u >> 16) & 1u)) >> 16;   // RNE
  return (unsigned short)r;
}

// ---------------- generic tiled GEMM: C = scale * A (*) B [+ addC] ---------
// BM=BN=64, BK=16, 256 threads, 4x4 micro. LDS stored k-major (transposed)
// so fragments load as ds_read_b128. transB=1: C=A*B^T ; 0: C=A*B
__global__ __launch_bounds__(256) void gemm_tile(
    const float* __restrict__ A, const float* __restrict__ B,
    float* __restrict__ C, const float* __restrict__ addC,
    const float* __restrict__ scale_ptr,
    int K, int lda, int ldb, int ldc, int ldadd,
    long sA, long sB, long sC, int transB) {
  __shared__ __align__(16) float As[16][68];
  __shared__ __align__(16) float Bs[16][68];
  const int tid = threadIdx.x;
  const int tx = tid & 15, ty = tid >> 4;
  const int m0 = blockIdx.y * 64, n0 = blockIdx.x * 64;
  const int b = blockIdx.z;
  A += (size_t)b * sA; B += (size_t)b * sB; C += (size_t)b * sC;
  float cc[4][4];
#pragma unroll
  for (int i = 0; i < 4; ++i)
#pragma unroll
    for (int j = 0; j < 4; ++j) cc[i][j] = 0.f;
  const int lr = tid >> 2, lc = (tid & 3) << 2;
  for (int k0 = 0; k0 < K; k0 += 16) {
    float4 av = *(const float4*)(A + (size_t)(m0 + lr) * lda + k0 + lc);
    As[lc][lr] = av.x; As[lc + 1][lr] = av.y; As[lc + 2][lr] = av.z; As[lc + 3][lr] = av.w;
    if (transB) {
      float4 bv = *(const float4*)(B + (size_t)(n0 + lr) * ldb + k0 + lc);
      Bs[lc][lr] = bv.x; Bs[lc + 1][lr] = bv.y; Bs[lc + 2][lr] = bv.z; Bs[lc + 3][lr] = bv.w;
    } else {
      int kk = tid & 15, n4 = (tid >> 4) << 2;
      float4 bv = *(const float4*)(B + (size_t)(k0 + kk) * ldb + n0 + n4);
      *(float4*)&Bs[kk][n4] = bv;
    }
    __syncthreads();
#pragma unroll
    for (int kk = 0; kk < 16; ++kk) {
      float4 a4 = *(const float4*)&As[kk][ty * 4];
      float4 b4 = *(const float4*)&Bs[kk][tx * 4];
      float a[4] = {a4.x, a4.y, a4.z, a4.w};
      float bb[4] = {b4.x, b4.y, b4.z, b4.w};
#pragma unroll
      for (int i = 0; i < 4; ++i)
#pragma unroll
        for (int j = 0; j < 4; ++j) cc[i][j] = fmaf(a[i], bb[j], cc[i][j]);
    }
    __syncthreads();
  }
  float scale = scale_ptr ? scale_ptr[b] : 1.0f;
#pragma unroll
  for (int i = 0; i < 4; ++i)
#pragma unroll
    for (int j = 0; j < 4; ++j) {
      int m = m0 + ty * 4 + i, n = n0 + tx * 4 + j;
      float v = cc[i][j] * scale;
      if (addC) v += addC[(size_t)m * ldadd + n];
      C[(size_t)m * ldc + n] = v;
    }
}

// ---------------- Gram partials: Gpart[k][blk] = Z_chunk^T Z_chunk ---------
__global__ __launch_bounds__(256) void gram_kernel(const float* __restrict__ Z,
                                                   float* __restrict__ Gpart) {
  __shared__ __align__(16) float Zs[64][68];
  const int k = blockIdx.y, tid = threadIdx.x;
  const int d0 = (tid & 15) * 4, e0 = (tid >> 4) * 4;
  float acc[4][4];
#pragma unroll
  for (int i = 0; i < 4; ++i)
#pragma unroll
    for (int j = 0; j < 4; ++j) acc[i][j] = 0.f;
  for (int c = 0; c < 4; ++c) {
    int nb = blockIdx.x * 256 + c * 64;
    for (int idx = tid; idx < 1024; idx += 256) {
      int rr = idx >> 4, c4 = (idx & 15) * 4;
      float4 v = *(const float4*)(Z + (size_t)(nb + rr) * 192 + k * 64 + c4);
      *(float4*)&Zs[rr][c4] = v;
    }
    __syncthreads();
    for (int rr = 0; rr < 64; ++rr) {
      float4 zd4 = *(const float4*)&Zs[rr][d0];
      float4 ze4 = *(const float4*)&Zs[rr][e0];
      float zd[4] = {zd4.x, zd4.y, zd4.z, zd4.w};
      float ze[4] = {ze4.x, ze4.y, ze4.z, ze4.w};
#pragma unroll
      for (int i = 0; i < 4; ++i)
#pragma unroll
        for (int j = 0; j < 4; ++j) acc[i][j] = fmaf(zd[i], ze[j], acc[i][j]);
    }
    __syncthreads();
  }
  float* g = Gpart + (size_t)(k * 32 + blockIdx.x) * 4096;
#pragma unroll
  for (int i = 0; i < 4; ++i)
#pragma unroll
    for (int j = 0; j < 4; ++j) g[(d0 + i) * 64 + (e0 + j)] = acc[i][j];
}

// ---------------- fused-dispatch helpers (256 threads) ---------------------
__device__ __forceinline__ float blocksum256(float v, volatile float* scr) {
#pragma unroll
  for (int o = 32; o; o >>= 1) v += __shfl_xor(v, o);
  __syncthreads();
  if ((threadIdx.x & 63) == 0) scr[threadIdx.x >> 6] = v;
  __syncthreads();
  return scr[0] + scr[1] + scr[2] + scr[3];
}

// C = X * Y for 64x64 with X symmetric (reads X rows via symmetry): b128 only.
__device__ __forceinline__ void gemm64s(const float* X, const float* Y,
                                        float acc[4][4]) {
  const int tx = threadIdx.x & 15, ty = threadIdx.x >> 4;
#pragma unroll
  for (int i = 0; i < 4; ++i)
#pragma unroll
    for (int j = 0; j < 4; ++j) acc[i][j] = 0.f;
  for (int kk = 0; kk < 64; ++kk) {
    float4 a4 = *(const float4*)&X[kk * 64 + ty * 4];   // X[ty*4+i][kk] (sym)
    float4 b4 = *(const float4*)&Y[kk * 64 + tx * 4];   // Y[kk][tx*4+j]
    float a[4] = {a4.x, a4.y, a4.z, a4.w};
    float bb[4] = {b4.x, b4.y, b4.z, b4.w};
#pragma unroll
    for (int i = 0; i < 4; ++i)
#pragma unroll
      for (int j = 0; j < 4; ++j) acc[i][j] = fmaf(a[i], bb[j], acc[i][j]);
  }
}

__device__ __forceinline__ void wb64(float* D, const float acc[4][4]) {
  const int tx = threadIdx.x & 15, ty = threadIdx.x >> 4;
#pragma unroll
  for (int i = 0; i < 4; ++i)
#pragma unroll
    for (int j = 0; j < 4; ++j) D[(ty * 4 + i) * 64 + tx * 4 + j] = acc[i][j];
}

__device__ __forceinline__ float dot64(const float* X, const float* Y, float* scr) {
  const int tx = threadIdx.x & 15, ty = threadIdx.x >> 4;
  float v = 0.f;
#pragma unroll
  for (int i = 0; i < 4; ++i)
#pragma unroll
    for (int j = 0; j < 4; ++j) {
      int idx = (ty * 4 + i) * 64 + tx * 4 + j;
      v += X[idx] * Y[idx];
    }
  return blocksum256(v, scr);
}

// ---------------- fused: split-K bf16 MFMA L@Hp  +  smallk -----------------
// grid 515 x 256 thr. blocks 0-2: smallk(k=bid). blocks 3-514: GEMM.
__global__ __launch_bounds__(256) void fused_big(
    const float* __restrict__ Lp, const unsigned short* __restrict__ HpT,
    float* __restrict__ Pbuf, const float* __restrict__ Gpart,
    float* __restrict__ Minv, float* __restrict__ Rout) {
  __shared__ __align__(16) float smem[12304];
  const int tid = threadIdx.x;

  if (blockIdx.x >= 3) {
    // ---------------- big GEMM path: BM=128,BN=128,BK=32 -------------------
    unsigned short (*As)[40] = (unsigned short(*)[40])smem;          // [128][40]
    unsigned short (*Bs)[40] = (unsigned short(*)[40])(smem + 2560); // [128][40]
    const int g = blockIdx.x - 3;
    const int m0 = (g & 63) * 128;
    const int split = g >> 6;
    const int kbase = split * 1024;
    const int wave = tid >> 6, lane = tid & 63;
    const int ar = tid >> 1, ah = (tid & 1) * 16;
    const size_t lrow = (size_t)(m0 + ar) * 8192;
    const size_t brow = (size_t)ar * 8192;
    f32x4 acc[2][8];
#pragma unroll
    for (int i = 0; i < 2; ++i)
#pragma unroll
      for (int j = 0; j < 8; ++j) acc[i][j] = (f32x4){0.f, 0.f, 0.f, 0.f};
    float4 apf[4];
    uint4 bpf[2];
    {
      const float* ap = Lp + lrow + kbase + ah;
      apf[0] = *(const float4*)(ap); apf[1] = *(const float4*)(ap + 4);
      apf[2] = *(const float4*)(ap + 8); apf[3] = *(const float4*)(ap + 12);
      const unsigned short* bp = HpT + brow + kbase + ah;
      bpf[0] = *(const uint4*)(bp); bpf[1] = *(const uint4*)(bp + 8);
    }
    const int quad = lane >> 4, mcol = lane & 15;
    for (int step = 0; step < 32; ++step) {
      __syncthreads();
      {
        __attribute__((aligned(16))) unsigned short tmp[16];
        const float* f = (const float*)apf;
#pragma unroll
        for (int i = 0; i < 16; ++i) tmp[i] = f2bf_bits(f[i]);
        *(uint4*)&As[ar][ah] = *(const uint4*)&tmp[0];
        *(uint4*)&As[ar][ah + 8] = *(const uint4*)&tmp[8];
        *(uint4*)&Bs[ar][ah] = bpf[0];
        *(uint4*)&Bs[ar][ah + 8] = bpf[1];
      }
      __syncthreads();
      if (step < 31) {  // prefetch next k-tile (overlaps MFMA)
        int kc = kbase + (step + 1) * 32;
        const float* ap = Lp + lrow + kc + ah;
        apf[0] = *(const float4*)(ap); apf[1] = *(const float4*)(ap + 4);
        apf[2] = *(const float4*)(ap + 8); apf[3] = *(const float4*)(ap + 12);
        const unsigned short* bp = HpT + brow + kc + ah;
        bpf[0] = *(const uint4*)(bp); bpf[1] = *(const uint4*)(bp + 8);
      }
      short8 af0 = *(const short8*)&As[wave * 32 + mcol][quad * 8];
      short8 af1 = *(const short8*)&As[wave * 32 + 16 + mcol][quad * 8];
#pragma unroll
      for (int nt = 0; nt < 8; ++nt) {
        short8 bf = *(const short8*)&Bs[nt * 16 + mcol][quad * 8];
        acc[0][nt] = __builtin_amdgcn_mfma_f32_16x16x32_bf16(af0, bf, acc[0][nt], 0, 0, 0);
        acc[1][nt] = __builtin_amdgcn_mfma_f32_16x16x32_bf16(af1, bf, acc[1][nt], 0, 0, 0);
      }
    }
    float* P = Pbuf + (size_t)split * 1048576;
#pragma unroll
    for (int mt = 0; mt < 2; ++mt)
#pragma unroll
      for (int nt = 0; nt < 8; ++nt)
#pragma unroll
        for (int r = 0; r < 4; ++r) {
          int grow = m0 + wave * 32 + mt * 16 + quad * 4 + r;
          int gcol = nt * 16 + mcol;
          P[(size_t)grow * 128 + gcol] = acc[mt][nt][r];
        }
    return;
  }

  // ---------------- smallk path: k = blockIdx.x ----------------------------
  const int k = blockIdx.x;
  float* B0 = smem;          // E
  float* B1 = smem + 4096;   // E2 -> X
  float* B2 = smem + 8192;   // E3 -> T
  float* scr = smem + 12288;
  // M = I + coeff * sum_b Gpart[k][b]
  for (int i = tid; i < 4096; i += 256) {
    float s = 0.f;
    const float* gp = Gpart + (size_t)k * 32 * 4096 + i;
    for (int b = 0; b < 32; ++b) s += gp[b * 4096];
    B0[i] = COEFF * s + ((i >> 6) == (i & 63) ? 1.f : 0.f);
  }
  __syncthreads();
  // Gershgorin bounds (wave 0; M symmetric, column==row sums)
  if (tid < 64) {
    float rs = 0.f, dg = B0[tid * 65];
    for (int j = 0; j < 64; ++j) rs += fabsf(B0[j * 64 + tid]);
    float lo = 2.f * dg - rs, hi = rs;
#pragma unroll
    for (int o = 32; o; o >>= 1) {
      lo = fminf(lo, __shfl_xor(lo, o));
      hi = fmaxf(hi, __shfl_xor(hi, o));
    }
    if (tid == 0) scr[4] = 0.5f * (fmaxf(lo, 1.f) + hi);
  }
  __syncthreads();
  const float alpha = scr[4], inva = 1.f / alpha;
  for (int i = tid; i < 4096; i += 256) {
    int r = i >> 6, c = i & 63;
    B0[i] = B0[i] * inva - (r == c ? 1.f : 0.f);   // E
  }
  __syncthreads();
  const int tx = tid & 15, ty = tid >> 4;
  float v1 = 0.f, v2 = 0.f;
#pragma unroll
  for (int i = 0; i < 4; ++i)
#pragma unroll
    for (int j = 0; j < 4; ++j) {
      int r = ty * 4 + i, c = tx * 4 + j;
      float e = B0[r * 64 + c];
      if (r == c) v1 += e;
      v2 += e * e;
    }
  float t1 = blocksum256(v1, scr);
  float t2 = blocksum256(v2, scr);
  float acc[4][4];
  gemm64s(B0, B0, acc); __syncthreads(); wb64(B1, acc); __syncthreads();  // E2
  float t3 = dot64(B1, B0, scr);
  float t4 = dot64(B1, B1, scr);
  gemm64s(B1, B0, acc); __syncthreads(); wb64(B2, acc); __syncthreads();  // E3
  float t5 = dot64(B2, B1, scr);
  float t6 = dot64(B2, B2, scr);
  gemm64s(B1, B1, acc);                                                   // E4 (regs)
  {
    float v7 = 0.f, v8 = 0.f;
#pragma unroll
    for (int i = 0; i < 4; ++i)
#pragma unroll
      for (int j = 0; j < 4; ++j) {
        int idx = (ty * 4 + i) * 64 + tx * 4 + j;
        v7 += acc[i][j] * B2[idx];
        v8 += acc[i][j] * acc[i][j];
      }
    float t7 = blocksum256(v7, scr);
    float t8 = blocksum256(v8, scr);
    if (tid == 0) {
      float ld = 64.f * logf(alpha) + t1 - t2 * 0.5f + t3 / 3.f - t4 * 0.25f
                 + t5 * 0.2f - t6 / 6.f + t7 / 7.f - t8 * 0.125f;
      Rout[k] = 0.5f * ld;
    }
  }
  // Newton-Schulz: X0 = I - E ; X <- X(2I - (I+E)X), 2 iters
  for (int i = tid; i < 4096; i += 256) {
    int r = i >> 6, c = i & 63;
    B1[i] = (r == c ? 1.f : 0.f) - B0[i];
  }
  __syncthreads();
  for (int it = 0; it < 2; ++it) {
    gemm64s(B0, B1, acc);       // E*X
    __syncthreads();
    {                           // T = E*X + X -> B2 (own elements)
#pragma unroll
      for (int i = 0; i < 4; ++i)
#pragma unroll
        for (int j = 0; j < 4; ++j) {
          int idx = (ty * 4 + i) * 64 + tx * 4 + j;
          B2[idx] = acc[i][j] + B1[idx];
        }
    }
    __syncthreads();
    gemm64s(B1, B2, acc);       // X*T
    __syncthreads();
    {                           // X = 2X - X*T (own elements)
#pragma unroll
      for (int i = 0; i < 4; ++i)
#pragma unroll
        for (int j = 0; j < 4; ++j) {
          int idx = (ty * 4 + i) * 64 + tx * 4 + j;
          B1[idx] = 2.f * B1[idx] - acc[i][j];
        }
    }
    __syncthreads();
  }
  for (int i = tid; i < 4096; i += 256) Minv[k * 4096 + i] = B1[i] * inva;
}

// ---------------- weights / tail outputs -----------------------------------
__global__ void small_w(const float* __restrict__ R, const float* __restrict__ tauP,
                        float* __restrict__ tail, float* __restrict__ sb) {
  if (threadIdx.x != 0) return;
  float R0 = R[0], R1 = R[1], R2 = R[2];
  float d0 = R0, d1 = R1 - R0, d2 = R2 - R1;
  float mean = (d0 + d1 + d2) * (1.f / 3.f);
  float e0 = d0 - mean, e1 = d1 - mean, e2 = d2 - mean;
  float sd = sqrtf((e0 * e0 + e1 * e1 + e2 * e2) * 0.5f) + 1e-6f;
  float n0 = e0 / sd, n1 = e1 / sd, n2 = e2 / sd;
  float tau = tauP[0];
  float x0 = n0 / tau, x1 = n1 / tau, x2 = n2 / tau;
  float mx = fmaxf(x0, fmaxf(x1, x2));
  float w0 = expf(x0 - mx), w1 = expf(x1 - mx), w2 = expf(x2 - mx);
  float s = w0 + w1 + w2;
  w0 /= s; w1 /= s; w2 /= s;
  tail[0] = w0; tail[1] = w1; tail[2] = w2;
  tail[3] = n0; tail[4] = n1; tail[5] = n2;
  tail[6] = d0; tail[7] = d1; tail[8] = d2;
  sb[0] = 0.015625f * w0; sb[1] = 0.015625f * w1; sb[2] = 0.015625f * w2;  // ETA*coeff*w
}

// ---------------- Hp -> HpT bf16 (transpose + convert) ---------------------
__global__ __launch_bounds__(256) void transpose_cvt(const float* __restrict__ Hp,
                                                     unsigned short* __restrict__ HpT) {
  __shared__ float T[32][33];
  const int cb = blockIdx.x, rb = blockIdx.y, tid = threadIdx.x;
  int r = tid >> 3, c4 = (tid & 7) * 4;
  float4 v = *(const float4*)(Hp + (size_t)(rb * 32 + r) * 128 + cb * 32 + c4);
  T[r][c4] = v.x; T[r][c4 + 1] = v.y; T[r][c4 + 2] = v.z; T[r][c4 + 3] = v.w;
  __syncthreads();
  int c = tid >> 3, r4 = (tid & 7) * 4;
  ushort4 u;
  u.x = f2bf_bits(T[r4][c]); u.y = f2bf_bits(T[r4 + 1][c]);
  u.z = f2bf_bits(T[r4 + 2][c]); u.w = f2bf_bits(T[r4 + 3][c]);
  *(ushort4*)(HpT + (size_t)(cb * 32 + c) * 8192 + rb * 32 + r4) = u;
}

// ---------------- split-K reduce + soft-threshold + LayerNorm --------------
__global__ __launch_bounds__(256) void finish_kernel(
    const float* __restrict__ pre, const float* __restrict__ Pbuf,
    const float* __restrict__ thr, const float* __restrict__ gamma,
    const float* __restrict__ beta, float* __restrict__ out) {
  const int lane = threadIdx.x & 63;
  const int row = blockIdx.x * 4 + (threadIdx.x >> 6);
  const size_t off = (size_t)row * 128;
  float l0 = 0.f, l1 = 0.f;
#pragma unroll
  for (int s = 0; s < 8; ++s) {
    l0 += Pbuf[s * 1048576 + off + lane];
    l1 += Pbuf[s * 1048576 + off + lane + 64];
  }
  float x0 = pre[off + lane] + SCL_LAP * l0;
  float x1 = pre[off + lane + 64] + SCL_LAP * l1;
  float t0 = fabsf(thr[lane]), t1 = fabsf(thr[lane + 64]);
  float a0 = fmaxf(fabsf(x0) - t0, 0.f); float s0 = (x0 >= 0.f) ? a0 : -a0;
  float a1 = fmaxf(fabsf(x1) - t1, 0.f); float s1 = (x1 >= 0.f) ? a1 : -a1;
  float sum = s0 + s1;
#pragma unroll
  for (int o = 32; o; o >>= 1) sum += __shfl_xor(sum, o);
  float mean = sum * (1.f / 128.f);
  float d0 = s0 - mean, d1 = s1 - mean;
  float ss = d0 * d0 + d1 * d1;
#pragma unroll
  for (int o = 32; o; o >>= 1) ss += __shfl_xor(ss, o);
  float inv = rsqrtf(ss * (1.f / 128.f) + 1e-5f);
  out[off + lane] = d0 * inv * gamma[lane] + beta[lane];
  out[off + lane + 64] = d1 * inv * gamma[lane + 64] + beta[lane + 64];
}

// ---------------------------------------------------------------------------
extern "C" void kernel_launch(void* const* d_in, const int* in_sizes, int n_in,
                              void* d_out, int out_size, void* d_ws, size_t ws_size,
                              hipStream_t stream) {
  const float* H = (const float*)d_in[0];
  const float* hop = (const float*)d_in[1];
  const float* L = (const float*)d_in[2];
  const float* Wst = (const float*)d_in[3];
  const float* Wout = (const float*)d_in[4];
  const float* thr = (const float*)d_in[5];
  const float* gamma = (const float*)d_in[6];
  const float* beta = (const float*)d_in[7];
  const float* tau = (const float*)d_in[8];
  float* out = (float*)d_out;

  float* ws = (float*)d_ws;
  float* Zbuf = ws;                       // [8192][192] packed Z (k*64+d)
  float* Hp = Zbuf + 1572864;             // [8192][128]
  float* pre = Hp + 1048576;              // [8192][128]
  float* Gpart = pre + 1048576;           // [3][32][4096]
  float* Minv = Gpart + 393216;           // [3][64][64]
  float* Rb = Minv + 12288;               // [3]
  float* sb = Rb + 16;                    // [3]
  float* Pb = sb + 16;                    // [3][128][64]
  float* QT = Pb + 24576;                 // [128][192] packed QT
  float* Pbuf = QT + 24576;               // [8][8192][128] split-K partials
  unsigned short* HpT = (unsigned short*)(Pbuf + 8388608);  // [128][8192] bf16

  // Hp = H @ W_out^T
  gemm_tile<<<dim3(2, 128, 1), 256, 0, stream>>>(
      H, Wout, Hp, nullptr, nullptr, 256, 256, 256, 128, 0, 0L, 0L, 0L, 1);
  // HpT bf16
  transpose_cvt<<<dim3(4, 256), 256, 0, stream>>>(Hp, HpT);
  // Z_k = hop_k @ W_k^T  -> Zbuf cols [k*64, k*64+64)
  gemm_tile<<<dim3(1, 128, 3), 256, 0, stream>>>(
      hop, Wst, Zbuf, nullptr, nullptr, 256, 256, 256, 192, 0,
      2097152L, 16384L, 64L, 1);
  // Gram partials
  gram_kernel<<<dim3(32, 3), 256, 0, stream>>>(Zbuf, Gpart);
  // P_k = W_out @ W_k^T (independent of smallk)
  gemm_tile<<<dim3(1, 2, 3), 256, 0, stream>>>(
      Wout, Wst, Pb, nullptr, nullptr, 256, 256, 256, 64, 0,
      0L, 16384L, 8192L, 1);
  // fused: smallk (blocks 0-2) + split-K L@Hp partials (blocks 3-514)
  fused_big<<<dim3(515), 256, 0, stream>>>(L, HpT, Pbuf, Gpart, Minv, Rb);
  // weights + tail outputs
  small_w<<<dim3(1), 64, 0, stream>>>(Rb, tau, out + 1048576, sb);
  // QT_k = s_k * P_k @ Minv_k  (Minv symmetric) -> QT cols [k*64, k*64+64)
  gemm_tile<<<dim3(1, 2, 3), 256, 0, stream>>>(
      Pb, Minv, QT, nullptr, sb, 64, 64, 64, 192, 0,
      8192L, 4096L, 64L, 0);
  // pre = Hp + Zbuf @ QT^T
  gemm_tile<<<dim3(2, 128, 1), 256, 0, stream>>>(
      Zbuf, QT, pre, Hp, nullptr, 192, 192, 192, 128, 128, 0L, 0L, 0L, 1);
  // out = LN(softthresh(pre - 0.15 * sum_s Pbuf[s]))
  finish_kernel<<<dim3(2048), 256, 0, stream>>>(pre, Pbuf, thr, gamma, beta, out);

  (void)in_sizes; (void)n_in; (void)out_size; (void)ws_size;
}